// Round 6
// baseline (665.545 us; speedup 1.0000x reference)
//
#include <hip/hip_runtime.h>
#include <math.h>

#define N_NODES 100000
#define N_EDGES 1600000
#define N_GRAPHS 128
#define IN_DIM 329
#define NH 4
#define CC 64
#define HC 256
#define NEG_SLOPE 0.2f

#define K_PAD 384            // 6 * 64
#define M_PAD 100096         // 782 * 128
#define SLOTS 64             // max in-degree+1 slots per node (Poisson(16): P(>64) ~ 1e-11)
#define NBUCK 196            // ceil(N/512) buckets of 512 nodes
#define BCAP 10240           // bucket capacity (expected 8673, +16 sigma)
#define SEG 3                // blocks per bucket in pass 2

typedef unsigned short u16;
typedef unsigned char u8;
typedef unsigned int u32;
typedef __attribute__((ext_vector_type(8))) short short8;   // 8 bf16 (4 VGPRs)
typedef __attribute__((ext_vector_type(4))) float floatx4;
typedef __attribute__((ext_vector_type(2))) float floatx2;

__device__ __forceinline__ u16 f2bf(float f) {
    u32 u = __float_as_uint(f);
    u32 r = (u + 0x7FFFu + ((u >> 16) & 1u)) >> 16;   // RNE
    return (u16)r;
}

// ---- fp8 e4m3 (OCP) helpers: HW path via cvt builtins, SW fallback --------
__device__ __forceinline__ u8 f2fp8(float f) {
#if __has_builtin(__builtin_amdgcn_cvt_pk_fp8_f32)
    int pk = __builtin_amdgcn_cvt_pk_fp8_f32(f, f, 0, false);
    return (u8)(pk & 0xFF);
#else
    u32 u = __float_as_uint(f);
    u32 sgn = (u >> 24) & 0x80;
    float af = fabsf(f);
    if (af >= 448.f) return (u8)(sgn | 0x7E);
    if (af < 0.015625f) {
        int m = (int)rintf(af * 512.f);
        if (m >= 8) return (u8)(sgn | 0x08);
        return (u8)(sgn | (u32)m);
    }
    u32 au = u & 0x7FFFFFFF;
    u32 r = au + 0x0007FFFFu + ((au >> 20) & 1u);
    u32 e = r >> 23;
    u32 m3 = (r >> 20) & 7;
    int fe = (int)e - 127 + 7;
    if (fe >= 16) return (u8)(sgn | 0x7E);
    return (u8)(sgn | ((u32)fe << 3) | m3);
#endif
}

__device__ __forceinline__ float fp82f_sw(u32 b) {
    u32 s = (b & 0x80u) << 24;
    u32 e = (b >> 3) & 0xF;
    u32 m = b & 7;
    if (e == 0) {
        float v = (float)m * 0.001953125f;
        return (b & 0x80) ? -v : v;
    }
    return __uint_as_float(s | ((e + 120) << 23) | (m << 20));
}

__device__ __forceinline__ floatx4 dec4(int p) {
#if __has_builtin(__builtin_amdgcn_cvt_pk_f32_fp8)
    floatx2 lo = __builtin_amdgcn_cvt_pk_f32_fp8(p, false);
    floatx2 hi = __builtin_amdgcn_cvt_pk_f32_fp8(p, true);
    floatx4 r; r.x = lo.x; r.y = lo.y; r.z = hi.x; r.w = hi.y;
    return r;
#else
    floatx4 r;
    r.x = fp82f_sw(p & 0xFF);  r.y = fp82f_sw((p >> 8) & 0xFF);
    r.z = fp82f_sw((p >> 16) & 0xFF); r.w = fp82f_sw((p >> 24) & 0xFF);
    return r;
#endif
}

__device__ __forceinline__ void async_copy16(const void* g, void* l) {
    __builtin_amdgcn_global_load_lds((const __attribute__((address_space(1))) void*)g,
                                     (__attribute__((address_space(3))) void*)l, 16, 0, 0);
}

__device__ __forceinline__ float sel4(float4 a, int h) {
    float lo = (h & 1) ? a.y : a.x;
    float hi = (h & 1) ? a.w : a.z;
    return (h & 2) ? hi : lo;
}

// ---------------------------------------------------------------------------
// Convert: x -> xb (bf16, padded), W -> WbT (bf16, transposed, padded).
// ---------------------------------------------------------------------------
__global__ __launch_bounds__(256) void convert_kernel(
    const float* __restrict__ x, const float* __restrict__ W,
    u16* __restrict__ xb, u16* __restrict__ WbT)
{
    const int xslots = M_PAD * (K_PAD / 4);
    int t = blockIdx.x * 256 + threadIdx.x;
    if (t < xslots) {
        int row = t / 96;
        int slot = t - row * 96;
        int k0 = slot * 4;
        ushort4 o = {0, 0, 0, 0};
        if (row < N_NODES) {
            const float* xr = x + (size_t)row * IN_DIM + k0;
            if (k0 + 3 < IN_DIM) {
                o.x = f2bf(xr[0]); o.y = f2bf(xr[1]); o.z = f2bf(xr[2]); o.w = f2bf(xr[3]);
            } else {
                if (k0 < IN_DIM)     o.x = f2bf(xr[0]);
                if (k0 + 1 < IN_DIM) o.y = f2bf(xr[1]);
                if (k0 + 2 < IN_DIM) o.z = f2bf(xr[2]);
            }
        }
        *(ushort4*)(xb + (size_t)row * K_PAD + k0) = o;
    } else {
        int i = t - xslots;
        if (i >= HC * 96) return;
        int c = i / 96;
        int slot = i - c * 96;
        int k0 = slot * 4;
        ushort4 o = {0, 0, 0, 0};
        const float* wp = W + c;
        if (k0 < IN_DIM)     o.x = f2bf(wp[(size_t)k0 * HC]);
        if (k0 + 1 < IN_DIM) o.y = f2bf(wp[(size_t)(k0 + 1) * HC]);
        if (k0 + 2 < IN_DIM) o.z = f2bf(wp[(size_t)(k0 + 2) * HC]);
        if (k0 + 3 < IN_DIM) o.w = f2bf(wp[(size_t)(k0 + 3) * HC]);
        *(ushort4*)(WbT + (size_t)c * K_PAD + k0) = o;
    }
}

// ---------------------------------------------------------------------------
// bf16 MFMA GEMM, BK=64, XOR-swizzled LDS; epilogue: fp8 xp store + fused
// a_src/a_dst attention dots (each wave's 64 cols == one head).
// ---------------------------------------------------------------------------
__global__ __launch_bounds__(256) void gemm_mfma_kernel(
    const u16* __restrict__ xb, const u16* __restrict__ WbT,
    const float* __restrict__ att_src, const float* __restrict__ att_dst,
    u8* __restrict__ xp8, float* __restrict__ a_src, float* __restrict__ a_dst)
{
    __shared__ u16 As[128 * 64];
    __shared__ u16 Bs[128 * 64];

    const int tid = threadIdx.x;
    const int lane = tid & 63;
    const int wave = tid >> 6;
    const int lr = lane & 15;
    const int q = lane >> 4;
    const int row0 = blockIdx.x * 128;
    const int col0 = blockIdx.y * 128;
    const int rm0 = (wave & 1) * 64;
    const int cn0 = (wave >> 1) * 64;

    floatx4 acc[4][4];
#pragma unroll
    for (int i = 0; i < 4; i++)
#pragma unroll
        for (int j = 0; j < 4; j++) {
            acc[i][j].x = 0.f; acc[i][j].y = 0.f; acc[i][j].z = 0.f; acc[i][j].w = 0.f;
        }

    for (int k0 = 0; k0 < K_PAD; k0 += 64) {
#pragma unroll
        for (int t = 0; t < 4; t++) {
            int off = (tid + t * 256) * 16;
            int row = off >> 7;
            int col = off & 127;
            int gcol = col ^ ((row & 7) * 16);
            const char* ga = (const char*)xb + (size_t)(row0 + row) * (K_PAD * 2) + k0 * 2 + gcol;
            async_copy16(ga, (char*)As + off);
            const char* gb = (const char*)WbT + (size_t)(col0 + row) * (K_PAD * 2) + k0 * 2 + gcol;
            async_copy16(gb, (char*)Bs + off);
        }
        __syncthreads();

        short8 af[2][4], bf[2][4];
#pragma unroll
        for (int ks = 0; ks < 2; ks++) {
#pragma unroll
            for (int i = 0; i < 4; i++) {
                int ra = rm0 + i * 16 + lr;
                int ca = (ks * 64 + q * 16) ^ ((ra & 7) * 16);
                af[ks][i] = *(const short8*)((const char*)As + ra * 128 + ca);
                int rb = cn0 + i * 16 + lr;
                int cb = (ks * 64 + q * 16) ^ ((rb & 7) * 16);
                bf[ks][i] = *(const short8*)((const char*)Bs + rb * 128 + cb);
            }
        }
#pragma unroll
        for (int ks = 0; ks < 2; ks++)
#pragma unroll
            for (int i = 0; i < 4; i++)
#pragma unroll
                for (int j = 0; j < 4; j++)
                    acc[i][j] = __builtin_amdgcn_mfma_f32_16x16x32_bf16(af[ks][i], bf[ks][j], acc[i][j], 0, 0, 0);
        __syncthreads();
    }

    const int h_w = (col0 + cn0) >> 6;
    float asj[4], adj[4];
#pragma unroll
    for (int j = 0; j < 4; j++) {
        asj[j] = att_src[h_w * 64 + j * 16 + lr];
        adj[j] = att_dst[h_w * 64 + j * 16 + lr];
    }
#pragma unroll
    for (int i = 0; i < 4; i++) {
        float psv[4] = {0, 0, 0, 0}, pdv[4] = {0, 0, 0, 0};
#pragma unroll
        for (int j = 0; j < 4; j++) {
            int col = col0 + cn0 + j * 16 + lr;
            float v[4] = {acc[i][j].x, acc[i][j].y, acc[i][j].z, acc[i][j].w};
#pragma unroll
            for (int r = 0; r < 4; r++) {
                psv[r] = fmaf(v[r], asj[j], psv[r]);
                pdv[r] = fmaf(v[r], adj[j], pdv[r]);
                int row = row0 + rm0 + i * 16 + q * 4 + r;
                if (row < N_NODES) xp8[(size_t)row * HC + col] = f2fp8(v[r]);
            }
        }
#pragma unroll
        for (int m = 1; m < 16; m <<= 1) {
#pragma unroll
            for (int r = 0; r < 4; r++) {
                psv[r] += __shfl_xor(psv[r], m, 64);
                pdv[r] += __shfl_xor(pdv[r], m, 64);
            }
        }
        if (lr == 0) {
#pragma unroll
            for (int r = 0; r < 4; r++) {
                int row = row0 + rm0 + i * 16 + q * 4 + r;
                if (row < N_NODES) {
                    a_src[row * 4 + h_w] = psv[r];
                    a_dst[row * 4 + h_w] = pdv[r];
                }
            }
        }
    }
}

// ---------------------------------------------------------------------------
// Pass 1: bin edges by dst>>9 into sequential bucket FIFOs. Bucket write
// heads advance sequentially -> L2 merges 8 records/line -> write amp ~1.
// bcur padded to one counter per 64B line.
// ---------------------------------------------------------------------------
__global__ void bin_kernel(const int* __restrict__ ei, int* __restrict__ bcur,
                           int2* __restrict__ bins)
{
    int i = blockIdx.x * blockDim.x + threadIdx.x;
    if (i >= N_EDGES + N_NODES) return;
    int s, d;
    if (i < N_EDGES) { s = ei[i]; d = ei[N_EDGES + i]; }
    else             { s = i - N_EDGES; d = s; }
    int b = d >> 9;
    int pos = atomicAdd(&bcur[b * 16], 1);
    if (pos < BCAP) {
        int2 v; v.x = s; v.y = d;
        bins[(size_t)b * BCAP + pos] = v;
    }
}

// ---------------------------------------------------------------------------
// Pass 2: per-bucket scatter into slotted csr. All stores land in the
// bucket's 131 KB csr window -> L2-resident, lines re-hit ~deg times.
// ---------------------------------------------------------------------------
__global__ __launch_bounds__(256) void fill2_kernel(
    const int* __restrict__ bcur, const int2* __restrict__ bins,
    int* __restrict__ cursor, int* __restrict__ csr)
{
    int blk = blockIdx.x;
    int b = blk / SEG, seg = blk - b * SEG;
    int cnt = min(bcur[b * 16], BCAP);
    int lo = (int)((long)cnt * seg / SEG);
    int hi = (int)((long)cnt * (seg + 1) / SEG);
    const int2* bp = bins + (size_t)b * BCAP;
    for (int e = lo + threadIdx.x; e < hi; e += 256) {
        int2 v = bp[e];
        int pos = atomicAdd(&cursor[v.y], 1);
        csr[(size_t)v.y * SLOTS + pos] = v.x;
    }
}

// ---------------------------------------------------------------------------
// Fused single-pass segment softmax + fp8 aggregation + head-mean + bias/relu.
// ---------------------------------------------------------------------------
__global__ __launch_bounds__(256) void aggregate_kernel(
    const u8* __restrict__ xp8, const float* __restrict__ a_src, const float* __restrict__ a_dst,
    const int* __restrict__ cursor, const int* __restrict__ csr,
    const float* __restrict__ bias, float* __restrict__ hbuf)
{
    int n = blockIdx.x * 4 + (threadIdx.x >> 6);
    int lane = threadIdx.x & 63;
    if (n >= N_NODES) return;
    int deg = __builtin_amdgcn_readfirstlane(cursor[n]);
    const int* ep = csr + (size_t)n * SLOTS;
    int h = lane >> 4;

    float ad = a_dst[n * 4 + h];
    const u8* xpl = xp8 + lane * 4;

    float acc0 = 0.f, acc1 = 0.f, acc2 = 0.f, acc3 = 0.f, den = 0.f;
    int e = 0;
    for (; e + 4 <= deg; e += 4) {
        int s0 = ep[e], s1 = ep[e + 1], s2 = ep[e + 2], s3 = ep[e + 3];
        float4 A0 = *(const float4*)(a_src + s0 * 4);
        float4 A1 = *(const float4*)(a_src + s1 * 4);
        float4 A2 = *(const float4*)(a_src + s2 * 4);
        float4 A3 = *(const float4*)(a_src + s3 * 4);
        int p0 = *(const int*)(xpl + (size_t)s0 * HC);
        int p1 = *(const int*)(xpl + (size_t)s1 * HC);
        int p2 = *(const int*)(xpl + (size_t)s2 * HC);
        int p3 = *(const int*)(xpl + (size_t)s3 * HC);
        float z0 = sel4(A0, h) + ad, z1 = sel4(A1, h) + ad;
        float z2 = sel4(A2, h) + ad, z3 = sel4(A3, h) + ad;
        float w0 = __expf(fmaxf(z0, NEG_SLOPE * z0));
        float w1 = __expf(fmaxf(z1, NEG_SLOPE * z1));
        float w2 = __expf(fmaxf(z2, NEG_SLOPE * z2));
        float w3 = __expf(fmaxf(z3, NEG_SLOPE * z3));
        den += (w0 + w1) + (w2 + w3);
        floatx4 v0 = dec4(p0), v1 = dec4(p1), v2 = dec4(p2), v3 = dec4(p3);
        acc0 = fmaf(w0, v0.x, acc0); acc1 = fmaf(w0, v0.y, acc1);
        acc2 = fmaf(w0, v0.z, acc2); acc3 = fmaf(w0, v0.w, acc3);
        acc0 = fmaf(w1, v1.x, acc0); acc1 = fmaf(w1, v1.y, acc1);
        acc2 = fmaf(w1, v1.z, acc2); acc3 = fmaf(w1, v1.w, acc3);
        acc0 = fmaf(w2, v2.x, acc0); acc1 = fmaf(w2, v2.y, acc1);
        acc2 = fmaf(w2, v2.z, acc2); acc3 = fmaf(w2, v2.w, acc3);
        acc0 = fmaf(w3, v3.x, acc0); acc1 = fmaf(w3, v3.y, acc1);
        acc2 = fmaf(w3, v3.z, acc2); acc3 = fmaf(w3, v3.w, acc3);
    }
    for (; e < deg; e++) {
        int s0 = ep[e];
        float4 A0 = *(const float4*)(a_src + s0 * 4);
        int p0 = *(const int*)(xpl + (size_t)s0 * HC);
        float z0 = sel4(A0, h) + ad;
        float w0 = __expf(fmaxf(z0, NEG_SLOPE * z0));
        den += w0;
        floatx4 v0 = dec4(p0);
        acc0 = fmaf(w0, v0.x, acc0); acc1 = fmaf(w0, v0.y, acc1);
        acc2 = fmaf(w0, v0.z, acc2); acc3 = fmaf(w0, v0.w, acc3);
    }

    float r = 1.f / den;
    acc0 *= r; acc1 *= r; acc2 *= r; acc3 *= r;
#pragma unroll
    for (int m = 16; m <= 32; m <<= 1) {
        acc0 += __shfl_xor(acc0, m, 64);
        acc1 += __shfl_xor(acc1, m, 64);
        acc2 += __shfl_xor(acc2, m, 64);
        acc3 += __shfl_xor(acc3, m, 64);
    }
    if (lane < 16) {
        const float* bp = bias + lane * 4;
        float4 o;
        o.x = fmaxf(0.25f * acc0 + bp[0], 0.f);
        o.y = fmaxf(0.25f * acc1 + bp[1], 0.f);
        o.z = fmaxf(0.25f * acc2 + bp[2], 0.f);
        o.w = fmaxf(0.25f * acc3 + bp[3], 0.f);
        *(float4*)&hbuf[(size_t)n * CC + lane * 4] = o;
    }
}

// ---------------------------------------------------------------------------
// Pool + MLP head (fused graph-bounds binary search; batch is sorted)
// ---------------------------------------------------------------------------
__global__ __launch_bounds__(256) void pool_mlp_kernel(
    const float* __restrict__ hbuf, const int* __restrict__ batch,
    const float* __restrict__ w1, const float* __restrict__ b1,
    const float* __restrict__ w2, const float* __restrict__ b2,
    float* __restrict__ out)
{
    int g = blockIdx.x;
    int tid = threadIdx.x;
    int lane = tid & 63;
    int w = tid >> 6;
    __shared__ int sb[2];
    __shared__ float red[4][64];
    __shared__ float gv[64];
    if (tid < 2) {
        int target = g + tid;
        int lo = 0, hi = N_NODES;
        while (lo < hi) {
            int mid = (lo + hi) >> 1;
            if (batch[mid] < target) lo = mid + 1; else hi = mid;
        }
        sb[tid] = lo;
    }
    __syncthreads();
    int start = sb[0], end = sb[1];
    int cnt = end - start;
    float sum = 0.f;
    for (int i = start + w; i < end; i += 4) sum += hbuf[(size_t)i * CC + lane];
    red[w][lane] = sum;
    __syncthreads();
    if (tid < 64) {
        float tot = red[0][lane] + red[1][lane] + red[2][lane] + red[3][lane];
        gv[lane] = tot / (float)max(cnt, 1);
    }
    __syncthreads();
    if (tid < 64) {
        float hid = b1[lane];
        for (int c = 0; c < 64; c++) hid = fmaf(gv[c], w1[c * 64 + lane], hid);
        hid = fmaxf(hid, 0.f);
        float part = hid * w2[lane];
#pragma unroll
        for (int off = 32; off > 0; off >>= 1) part += __shfl_xor(part, off, 64);
        if (lane == 0) out[g] = 1.f / (1.f + __expf(-(part + b2[0])));
    }
}

// ---------------------------------------------------------------------------
extern "C" void kernel_launch(void* const* d_in, const int* in_sizes, int n_in,
                              void* d_out, int out_size, void* d_ws, size_t ws_size,
                              hipStream_t stream)
{
    const float* x       = (const float*)d_in[0];
    const float* W       = (const float*)d_in[1];
    const float* att_src = (const float*)d_in[2];
    const float* att_dst = (const float*)d_in[3];
    const float* bias    = (const float*)d_in[4];
    const float* w1      = (const float*)d_in[5];
    const float* b1      = (const float*)d_in[6];
    const float* w2      = (const float*)d_in[7];
    const float* b2      = (const float*)d_in[8];
    const int*   ei      = (const int*)d_in[9];
    const int*   batch   = (const int*)d_in[10];
    float* out = (float*)d_out;

    char* ws = (char*)d_ws;
    size_t off = 0;
    auto alloc = [&](size_t bytes) -> void* {
        void* p = ws + off;
        off += (bytes + 255) & ~(size_t)255;
        return p;
    };
    u16*   xb        = (u16*)alloc((size_t)M_PAD * K_PAD * 2);          // 76.9 MB
    u16*   WbT       = (u16*)alloc((size_t)HC * K_PAD * 2);             // 196 KB
    u8*    xp8       = (u8*)alloc((size_t)N_NODES * HC);                // 25.6 MB
    float* a_src_b   = (float*)alloc((size_t)N_NODES * NH * 4);
    float* a_dst_b   = (float*)alloc((size_t)N_NODES * NH * 4);
    size_t zoff0 = off;
    int*   cursor    = (int*)alloc((size_t)N_NODES * 4);                // zeroed
    int*   bcur      = (int*)alloc((size_t)NBUCK * 16 * 4);             // zeroed
    size_t zbytes = off - zoff0;
    int2*  bins      = (int2*)alloc((size_t)NBUCK * BCAP * 8);          // 16.1 MB
    int*   csr       = (int*)alloc((size_t)N_NODES * SLOTS * 4);        // 25.6 MB
    float* hbuf      = (float*)xb;   // alias: xb dead after the GEMM

    hipMemsetAsync(cursor, 0, zbytes, stream);

    const int xslots = M_PAD * (K_PAD / 4);
    convert_kernel<<<(xslots + HC * 96 + 255) / 256, 256, 0, stream>>>(x, W, xb, WbT);

    dim3 ggrid(M_PAD / 128, 2);
    gemm_mfma_kernel<<<ggrid, 256, 0, stream>>>(xb, WbT, att_src, att_dst,
                                                xp8, a_src_b, a_dst_b);

    int tot = N_EDGES + N_NODES;
    bin_kernel<<<(tot + 255) / 256, 256, 0, stream>>>(ei, bcur, bins);
    fill2_kernel<<<NBUCK * SEG, 256, 0, stream>>>(bcur, bins, cursor, csr);

    aggregate_kernel<<<(N_NODES + 3) / 4, 256, 0, stream>>>(xp8, a_src_b, a_dst_b,
                                                            cursor, csr, bias, hbuf);

    pool_mlp_kernel<<<N_GRAPHS, 256, 0, stream>>>(hbuf, batch, w1, b1, w2, b2, out);
}

// Round 7
// 463.464 us; speedup vs baseline: 1.4360x; 1.4360x over previous
//
#include <hip/hip_runtime.h>
#include <math.h>

#define N_NODES 100000
#define N_EDGES 1600000
#define N_GRAPHS 128
#define IN_DIM 329
#define NH 4
#define CC 64
#define HC 256
#define NEG_SLOPE 0.2f

#define K_PAD 384            // 6 * 64
#define M_PAD 100096         // 782 * 128
#define NBUCK 196            // ceil(N/512) buckets of 512 nodes
#define BCAP 10240           // bucket capacity (expected 8673, +16 sigma)
#define EPB 4096             // edges per bin2 block

typedef unsigned short u16;
typedef unsigned char u8;
typedef unsigned int u32;
typedef __attribute__((ext_vector_type(8))) short short8;   // 8 bf16 (4 VGPRs)
typedef __attribute__((ext_vector_type(4))) float floatx4;
typedef __attribute__((ext_vector_type(2))) float floatx2;

__device__ __forceinline__ u16 f2bf(float f) {
    u32 u = __float_as_uint(f);
    u32 r = (u + 0x7FFFu + ((u >> 16) & 1u)) >> 16;   // RNE
    return (u16)r;
}

// ---- fp8 e4m3 (OCP) helpers: HW path via cvt builtins, SW fallback --------
__device__ __forceinline__ u8 f2fp8(float f) {
#if __has_builtin(__builtin_amdgcn_cvt_pk_fp8_f32)
    int pk = __builtin_amdgcn_cvt_pk_fp8_f32(f, f, 0, false);
    return (u8)(pk & 0xFF);
#else
    u32 u = __float_as_uint(f);
    u32 sgn = (u >> 24) & 0x80;
    float af = fabsf(f);
    if (af >= 448.f) return (u8)(sgn | 0x7E);
    if (af < 0.015625f) {
        int m = (int)rintf(af * 512.f);
        if (m >= 8) return (u8)(sgn | 0x08);
        return (u8)(sgn | (u32)m);
    }
    u32 au = u & 0x7FFFFFFF;
    u32 r = au + 0x0007FFFFu + ((au >> 20) & 1u);
    u32 e = r >> 23;
    u32 m3 = (r >> 20) & 7;
    int fe = (int)e - 127 + 7;
    if (fe >= 16) return (u8)(sgn | 0x7E);
    return (u8)(sgn | ((u32)fe << 3) | m3);
#endif
}

__device__ __forceinline__ float fp82f_sw(u32 b) {
    u32 s = (b & 0x80u) << 24;
    u32 e = (b >> 3) & 0xF;
    u32 m = b & 7;
    if (e == 0) {
        float v = (float)m * 0.001953125f;
        return (b & 0x80) ? -v : v;
    }
    return __uint_as_float(s | ((e + 120) << 23) | (m << 20));
}

__device__ __forceinline__ floatx4 dec4(int p) {
#if __has_builtin(__builtin_amdgcn_cvt_pk_f32_fp8)
    floatx2 lo = __builtin_amdgcn_cvt_pk_f32_fp8(p, false);
    floatx2 hi = __builtin_amdgcn_cvt_pk_f32_fp8(p, true);
    floatx4 r; r.x = lo.x; r.y = lo.y; r.z = hi.x; r.w = hi.y;
    return r;
#else
    floatx4 r;
    r.x = fp82f_sw(p & 0xFF);  r.y = fp82f_sw((p >> 8) & 0xFF);
    r.z = fp82f_sw((p >> 16) & 0xFF); r.w = fp82f_sw((p >> 24) & 0xFF);
    return r;
#endif
}

__device__ __forceinline__ void async_copy16(const void* g, void* l) {
    __builtin_amdgcn_global_load_lds((const __attribute__((address_space(1))) void*)g,
                                     (__attribute__((address_space(3))) void*)l, 16, 0, 0);
}

__device__ __forceinline__ float sel4(float4 a, int h) {
    float lo = (h & 1) ? a.y : a.x;
    float hi = (h & 1) ? a.w : a.z;
    return (h & 2) ? hi : lo;
}

// ---------------------------------------------------------------------------
// Convert: x -> xb (bf16, padded), W -> WbT (bf16, transposed, padded).
// ---------------------------------------------------------------------------
__global__ __launch_bounds__(256) void convert_kernel(
    const float* __restrict__ x, const float* __restrict__ W,
    u16* __restrict__ xb, u16* __restrict__ WbT)
{
    const int xslots = M_PAD * (K_PAD / 4);
    int t = blockIdx.x * 256 + threadIdx.x;
    if (t < xslots) {
        int row = t / 96;
        int slot = t - row * 96;
        int k0 = slot * 4;
        ushort4 o = {0, 0, 0, 0};
        if (row < N_NODES) {
            const float* xr = x + (size_t)row * IN_DIM + k0;
            if (k0 + 3 < IN_DIM) {
                o.x = f2bf(xr[0]); o.y = f2bf(xr[1]); o.z = f2bf(xr[2]); o.w = f2bf(xr[3]);
            } else {
                if (k0 < IN_DIM)     o.x = f2bf(xr[0]);
                if (k0 + 1 < IN_DIM) o.y = f2bf(xr[1]);
                if (k0 + 2 < IN_DIM) o.z = f2bf(xr[2]);
            }
        }
        *(ushort4*)(xb + (size_t)row * K_PAD + k0) = o;
    } else {
        int i = t - xslots;
        if (i >= HC * 96) return;
        int c = i / 96;
        int slot = i - c * 96;
        int k0 = slot * 4;
        ushort4 o = {0, 0, 0, 0};
        const float* wp = W + c;
        if (k0 < IN_DIM)     o.x = f2bf(wp[(size_t)k0 * HC]);
        if (k0 + 1 < IN_DIM) o.y = f2bf(wp[(size_t)(k0 + 1) * HC]);
        if (k0 + 2 < IN_DIM) o.z = f2bf(wp[(size_t)(k0 + 2) * HC]);
        if (k0 + 3 < IN_DIM) o.w = f2bf(wp[(size_t)(k0 + 3) * HC]);
        *(ushort4*)(WbT + (size_t)c * K_PAD + k0) = o;
    }
}

// ---------------------------------------------------------------------------
// bf16 MFMA GEMM, BK=64, XOR-swizzled LDS; epilogue: fp8 xp store + fused
// a_src/a_dst attention dots (each wave's 64 cols == one head).
// ---------------------------------------------------------------------------
__global__ __launch_bounds__(256) void gemm_mfma_kernel(
    const u16* __restrict__ xb, const u16* __restrict__ WbT,
    const float* __restrict__ att_src, const float* __restrict__ att_dst,
    u8* __restrict__ xp8, float* __restrict__ a_src, float* __restrict__ a_dst)
{
    __shared__ u16 As[128 * 64];
    __shared__ u16 Bs[128 * 64];

    const int tid = threadIdx.x;
    const int lane = tid & 63;
    const int wave = tid >> 6;
    const int lr = lane & 15;
    const int q = lane >> 4;
    const int row0 = blockIdx.x * 128;
    const int col0 = blockIdx.y * 128;
    const int rm0 = (wave & 1) * 64;
    const int cn0 = (wave >> 1) * 64;

    floatx4 acc[4][4];
#pragma unroll
    for (int i = 0; i < 4; i++)
#pragma unroll
        for (int j = 0; j < 4; j++) {
            acc[i][j].x = 0.f; acc[i][j].y = 0.f; acc[i][j].z = 0.f; acc[i][j].w = 0.f;
        }

    for (int k0 = 0; k0 < K_PAD; k0 += 64) {
#pragma unroll
        for (int t = 0; t < 4; t++) {
            int off = (tid + t * 256) * 16;
            int row = off >> 7;
            int col = off & 127;
            int gcol = col ^ ((row & 7) * 16);
            const char* ga = (const char*)xb + (size_t)(row0 + row) * (K_PAD * 2) + k0 * 2 + gcol;
            async_copy16(ga, (char*)As + off);
            const char* gb = (const char*)WbT + (size_t)(col0 + row) * (K_PAD * 2) + k0 * 2 + gcol;
            async_copy16(gb, (char*)Bs + off);
        }
        __syncthreads();

        short8 af[2][4], bf[2][4];
#pragma unroll
        for (int ks = 0; ks < 2; ks++) {
#pragma unroll
            for (int i = 0; i < 4; i++) {
                int ra = rm0 + i * 16 + lr;
                int ca = (ks * 64 + q * 16) ^ ((ra & 7) * 16);
                af[ks][i] = *(const short8*)((const char*)As + ra * 128 + ca);
                int rb = cn0 + i * 16 + lr;
                int cb = (ks * 64 + q * 16) ^ ((rb & 7) * 16);
                bf[ks][i] = *(const short8*)((const char*)Bs + rb * 128 + cb);
            }
        }
#pragma unroll
        for (int ks = 0; ks < 2; ks++)
#pragma unroll
            for (int i = 0; i < 4; i++)
#pragma unroll
                for (int j = 0; j < 4; j++)
                    acc[i][j] = __builtin_amdgcn_mfma_f32_16x16x32_bf16(af[ks][i], bf[ks][j], acc[i][j], 0, 0, 0);
        __syncthreads();
    }

    const int h_w = (col0 + cn0) >> 6;
    float asj[4], adj[4];
#pragma unroll
    for (int j = 0; j < 4; j++) {
        asj[j] = att_src[h_w * 64 + j * 16 + lr];
        adj[j] = att_dst[h_w * 64 + j * 16 + lr];
    }
#pragma unroll
    for (int i = 0; i < 4; i++) {
        float psv[4] = {0, 0, 0, 0}, pdv[4] = {0, 0, 0, 0};
#pragma unroll
        for (int j = 0; j < 4; j++) {
            int col = col0 + cn0 + j * 16 + lr;
            float v[4] = {acc[i][j].x, acc[i][j].y, acc[i][j].z, acc[i][j].w};
#pragma unroll
            for (int r = 0; r < 4; r++) {
                psv[r] = fmaf(v[r], asj[j], psv[r]);
                pdv[r] = fmaf(v[r], adj[j], pdv[r]);
                int row = row0 + rm0 + i * 16 + q * 4 + r;
                if (row < N_NODES) xp8[(size_t)row * HC + col] = f2fp8(v[r]);
            }
        }
#pragma unroll
        for (int m = 1; m < 16; m <<= 1) {
#pragma unroll
            for (int r = 0; r < 4; r++) {
                psv[r] += __shfl_xor(psv[r], m, 64);
                pdv[r] += __shfl_xor(pdv[r], m, 64);
            }
        }
        if (lr == 0) {
#pragma unroll
            for (int r = 0; r < 4; r++) {
                int row = row0 + rm0 + i * 16 + q * 4 + r;
                if (row < N_NODES) {
                    a_src[row * 4 + h_w] = psv[r];
                    a_dst[row * 4 + h_w] = pdv[r];
                }
            }
        }
    }
}

// ---------------------------------------------------------------------------
// Pass 1: block-local LDS binning. Each block sorts its 4096-edge slice by
// bucket in LDS, reserves one contiguous global range per bucket, streams the
// sorted records out -> all global stores are coalesced runs (~21 records).
// ---------------------------------------------------------------------------
__global__ __launch_bounds__(256) void bin2_kernel(
    const int* __restrict__ ei, int* __restrict__ bcur, int2* __restrict__ bins)
{
    __shared__ int hist[NBUCK];
    __shared__ int lofs[NBUCK];
    __shared__ int gpos[NBUCK];
    __shared__ int lcur[NBUCK];
    __shared__ int sc[256];
    __shared__ int2 lbuf[EPB];

    const int t = threadIdx.x;
    const int lo = blockIdx.x * EPB;
    const int hi = min(lo + EPB, N_EDGES + N_NODES);

    for (int b = t; b < NBUCK; b += 256) hist[b] = 0;
    __syncthreads();

    for (int i = lo + t; i < hi; i += 256) {
        int d = (i < N_EDGES) ? ei[N_EDGES + i] : (i - N_EDGES);
        atomicAdd(&hist[d >> 9], 1);
    }
    __syncthreads();

    int v = (t < NBUCK) ? hist[t] : 0;
    sc[t] = v;
    __syncthreads();
    for (int off = 1; off < 256; off <<= 1) {
        int u = (t >= off) ? sc[t - off] : 0;
        __syncthreads();
        sc[t] += u;
        __syncthreads();
    }
    if (t < NBUCK) {
        int excl = sc[t] - v;
        lofs[t] = excl;
        lcur[t] = excl;
        gpos[t] = atomicAdd(&bcur[t], v);
    }
    __syncthreads();

    for (int i = lo + t; i < hi; i += 256) {
        int s, d;
        if (i < N_EDGES) { s = ei[i]; d = ei[N_EDGES + i]; }
        else             { s = i - N_EDGES; d = s; }
        int b = d >> 9;
        int pos = atomicAdd(&lcur[b], 1);
        int2 r; r.x = s; r.y = d;
        lbuf[pos] = r;
    }
    __syncthreads();

    int total = hi - lo;
    for (int i = t; i < total; i += 256) {
        int2 r = lbuf[i];
        int b = r.y >> 9;
        int ob = gpos[b] + (i - lofs[b]);
        if (ob < BCAP) bins[(size_t)b * BCAP + ob] = r;
    }
}

// ---------------------------------------------------------------------------
// Pass 2: one block per bucket. LDS counting sort of ~8.7K records over the
// bucket's 512 nodes -> compact CSR written sequentially + rs_deg[n].
// ---------------------------------------------------------------------------
__global__ __launch_bounds__(256) void fill3_kernel(
    const int* __restrict__ bcur, const int2* __restrict__ bins,
    int2* __restrict__ rs_deg, int* __restrict__ csr)
{
    __shared__ int deg[512];
    __shared__ int cur[512];
    __shared__ int sc[256];
    __shared__ int order[BCAP];

    const int t = threadIdx.x;
    const int b = blockIdx.x;
    const int cnt = min(bcur[b], BCAP);
    const int2* bp = bins + (size_t)b * BCAP;
    const int gbase = b * BCAP;

    deg[t] = 0; deg[t + 256] = 0;
    __syncthreads();
    for (int i = t; i < cnt; i += 256) atomicAdd(&deg[bp[i].y & 511], 1);
    __syncthreads();

    int d0 = deg[2 * t], d1 = deg[2 * t + 1];
    sc[t] = d0 + d1;
    __syncthreads();
    for (int off = 1; off < 256; off <<= 1) {
        int u = (t >= off) ? sc[t - off] : 0;
        __syncthreads();
        sc[t] += u;
        __syncthreads();
    }
    int excl = sc[t] - (d0 + d1);
    cur[2 * t] = excl;
    cur[2 * t + 1] = excl + d0;
    int n0 = b * 512 + 2 * t;
    if (n0 < N_NODES)     { int2 rd; rd.x = gbase + excl;      rd.y = d0; rs_deg[n0] = rd; }
    if (n0 + 1 < N_NODES) { int2 rd; rd.x = gbase + excl + d0; rd.y = d1; rs_deg[n0 + 1] = rd; }
    __syncthreads();

    for (int i = t; i < cnt; i += 256) {
        int2 r = bp[i];
        int pos = atomicAdd(&cur[r.y & 511], 1);
        order[pos] = r.x;
    }
    __syncthreads();

    for (int i = t; i < cnt; i += 256) csr[gbase + i] = order[i];
}

// ---------------------------------------------------------------------------
// Fused single-pass segment softmax + fp8 aggregation + head-mean + bias/relu.
// ---------------------------------------------------------------------------
__global__ __launch_bounds__(256) void aggregate_kernel(
    const u8* __restrict__ xp8, const float* __restrict__ a_src, const float* __restrict__ a_dst,
    const int2* __restrict__ rs_deg, const int* __restrict__ csr,
    const float* __restrict__ bias, float* __restrict__ hbuf)
{
    int n = blockIdx.x * 4 + (threadIdx.x >> 6);
    int lane = threadIdx.x & 63;
    if (n >= N_NODES) return;
    int2 rd = rs_deg[n];
    int rstart = __builtin_amdgcn_readfirstlane(rd.x);
    int deg    = __builtin_amdgcn_readfirstlane(rd.y);
    const int* ep = csr + rstart;
    int h = lane >> 4;

    float ad = a_dst[n * 4 + h];
    const u8* xpl = xp8 + lane * 4;

    float acc0 = 0.f, acc1 = 0.f, acc2 = 0.f, acc3 = 0.f, den = 0.f;
    int e = 0;
    for (; e + 4 <= deg; e += 4) {
        int s0 = ep[e], s1 = ep[e + 1], s2 = ep[e + 2], s3 = ep[e + 3];
        float4 A0 = *(const float4*)(a_src + s0 * 4);
        float4 A1 = *(const float4*)(a_src + s1 * 4);
        float4 A2 = *(const float4*)(a_src + s2 * 4);
        float4 A3 = *(const float4*)(a_src + s3 * 4);
        int p0 = *(const int*)(xpl + (size_t)s0 * HC);
        int p1 = *(const int*)(xpl + (size_t)s1 * HC);
        int p2 = *(const int*)(xpl + (size_t)s2 * HC);
        int p3 = *(const int*)(xpl + (size_t)s3 * HC);
        float z0 = sel4(A0, h) + ad, z1 = sel4(A1, h) + ad;
        float z2 = sel4(A2, h) + ad, z3 = sel4(A3, h) + ad;
        float w0 = __expf(fmaxf(z0, NEG_SLOPE * z0));
        float w1 = __expf(fmaxf(z1, NEG_SLOPE * z1));
        float w2 = __expf(fmaxf(z2, NEG_SLOPE * z2));
        float w3 = __expf(fmaxf(z3, NEG_SLOPE * z3));
        den += (w0 + w1) + (w2 + w3);
        floatx4 v0 = dec4(p0), v1 = dec4(p1), v2 = dec4(p2), v3 = dec4(p3);
        acc0 = fmaf(w0, v0.x, acc0); acc1 = fmaf(w0, v0.y, acc1);
        acc2 = fmaf(w0, v0.z, acc2); acc3 = fmaf(w0, v0.w, acc3);
        acc0 = fmaf(w1, v1.x, acc0); acc1 = fmaf(w1, v1.y, acc1);
        acc2 = fmaf(w1, v1.z, acc2); acc3 = fmaf(w1, v1.w, acc3);
        acc0 = fmaf(w2, v2.x, acc0); acc1 = fmaf(w2, v2.y, acc1);
        acc2 = fmaf(w2, v2.z, acc2); acc3 = fmaf(w2, v2.w, acc3);
        acc0 = fmaf(w3, v3.x, acc0); acc1 = fmaf(w3, v3.y, acc1);
        acc2 = fmaf(w3, v3.z, acc2); acc3 = fmaf(w3, v3.w, acc3);
    }
    for (; e < deg; e++) {
        int s0 = ep[e];
        float4 A0 = *(const float4*)(a_src + s0 * 4);
        int p0 = *(const int*)(xpl + (size_t)s0 * HC);
        float z0 = sel4(A0, h) + ad;
        float w0 = __expf(fmaxf(z0, NEG_SLOPE * z0));
        den += w0;
        floatx4 v0 = dec4(p0);
        acc0 = fmaf(w0, v0.x, acc0); acc1 = fmaf(w0, v0.y, acc1);
        acc2 = fmaf(w0, v0.z, acc2); acc3 = fmaf(w0, v0.w, acc3);
    }

    float r = 1.f / den;
    acc0 *= r; acc1 *= r; acc2 *= r; acc3 *= r;
#pragma unroll
    for (int m = 16; m <= 32; m <<= 1) {
        acc0 += __shfl_xor(acc0, m, 64);
        acc1 += __shfl_xor(acc1, m, 64);
        acc2 += __shfl_xor(acc2, m, 64);
        acc3 += __shfl_xor(acc3, m, 64);
    }
    if (lane < 16) {
        const float* bp = bias + lane * 4;
        float4 o;
        o.x = fmaxf(0.25f * acc0 + bp[0], 0.f);
        o.y = fmaxf(0.25f * acc1 + bp[1], 0.f);
        o.z = fmaxf(0.25f * acc2 + bp[2], 0.f);
        o.w = fmaxf(0.25f * acc3 + bp[3], 0.f);
        *(float4*)&hbuf[(size_t)n * CC + lane * 4] = o;
    }
}

// ---------------------------------------------------------------------------
// Pool + MLP head (fused graph-bounds binary search; batch is sorted)
// ---------------------------------------------------------------------------
__global__ __launch_bounds__(256) void pool_mlp_kernel(
    const float* __restrict__ hbuf, const int* __restrict__ batch,
    const float* __restrict__ w1, const float* __restrict__ b1,
    const float* __restrict__ w2, const float* __restrict__ b2,
    float* __restrict__ out)
{
    int g = blockIdx.x;
    int tid = threadIdx.x;
    int lane = tid & 63;
    int w = tid >> 6;
    __shared__ int sb[2];
    __shared__ float red[4][64];
    __shared__ float gv[64];
    if (tid < 2) {
        int target = g + tid;
        int lo = 0, hi = N_NODES;
        while (lo < hi) {
            int mid = (lo + hi) >> 1;
            if (batch[mid] < target) lo = mid + 1; else hi = mid;
        }
        sb[tid] = lo;
    }
    __syncthreads();
    int start = sb[0], end = sb[1];
    int cnt = end - start;
    float sum = 0.f;
    for (int i = start + w; i < end; i += 4) sum += hbuf[(size_t)i * CC + lane];
    red[w][lane] = sum;
    __syncthreads();
    if (tid < 64) {
        float tot = red[0][lane] + red[1][lane] + red[2][lane] + red[3][lane];
        gv[lane] = tot / (float)max(cnt, 1);
    }
    __syncthreads();
    if (tid < 64) {
        float hid = b1[lane];
        for (int c = 0; c < 64; c++) hid = fmaf(gv[c], w1[c * 64 + lane], hid);
        hid = fmaxf(hid, 0.f);
        float part = hid * w2[lane];
#pragma unroll
        for (int off = 32; off > 0; off >>= 1) part += __shfl_xor(part, off, 64);
        if (lane == 0) out[g] = 1.f / (1.f + __expf(-(part + b2[0])));
    }
}

// ---------------------------------------------------------------------------
extern "C" void kernel_launch(void* const* d_in, const int* in_sizes, int n_in,
                              void* d_out, int out_size, void* d_ws, size_t ws_size,
                              hipStream_t stream)
{
    const float* x       = (const float*)d_in[0];
    const float* W       = (const float*)d_in[1];
    const float* att_src = (const float*)d_in[2];
    const float* att_dst = (const float*)d_in[3];
    const float* bias    = (const float*)d_in[4];
    const float* w1      = (const float*)d_in[5];
    const float* b1      = (const float*)d_in[6];
    const float* w2      = (const float*)d_in[7];
    const float* b2      = (const float*)d_in[8];
    const int*   ei      = (const int*)d_in[9];
    const int*   batch   = (const int*)d_in[10];
    float* out = (float*)d_out;

    char* ws = (char*)d_ws;
    size_t off = 0;
    auto alloc = [&](size_t bytes) -> void* {
        void* p = ws + off;
        off += (bytes + 255) & ~(size_t)255;
        return p;
    };
    u16*   xb        = (u16*)alloc((size_t)M_PAD * K_PAD * 2);          // 76.9 MB
    u16*   WbT       = (u16*)alloc((size_t)HC * K_PAD * 2);             // 196 KB
    u8*    xp8       = (u8*)alloc((size_t)N_NODES * HC);                // 25.6 MB
    float* a_src_b   = (float*)alloc((size_t)N_NODES * NH * 4);
    float* a_dst_b   = (float*)alloc((size_t)N_NODES * NH * 4);
    int*   bcur      = (int*)alloc((size_t)NBUCK * 4);                  // zeroed
    int2*  bins      = (int2*)alloc((size_t)NBUCK * BCAP * 8);          // 16.1 MB
    int2*  rs_deg    = (int2*)alloc((size_t)N_NODES * 8);               // 800 KB
    int*   csr       = (int*)alloc((size_t)NBUCK * BCAP * 4);           // 8 MB
    float* hbuf      = (float*)xb;   // alias: xb dead after the GEMM

    hipMemsetAsync(bcur, 0, (size_t)NBUCK * 4, stream);

    const int xslots = M_PAD * (K_PAD / 4);
    convert_kernel<<<(xslots + HC * 96 + 255) / 256, 256, 0, stream>>>(x, W, xb, WbT);

    dim3 ggrid(M_PAD / 128, 2);
    gemm_mfma_kernel<<<ggrid, 256, 0, stream>>>(xb, WbT, att_src, att_dst,
                                                xp8, a_src_b, a_dst_b);

    int tot = N_EDGES + N_NODES;
    bin2_kernel<<<(tot + EPB - 1) / EPB, 256, 0, stream>>>(ei, bcur, bins);
    fill3_kernel<<<NBUCK, 256, 0, stream>>>(bcur, bins, rs_deg, csr);

    aggregate_kernel<<<(N_NODES + 3) / 4, 256, 0, stream>>>(xp8, a_src_b, a_dst_b,
                                                            rs_deg, csr, bias, hbuf);

    pool_mlp_kernel<<<N_GRAPHS, 256, 0, stream>>>(hbuf, batch, w1, b1, w2, b2, out);
}

// Round 8
// 427.856 us; speedup vs baseline: 1.5555x; 1.0832x over previous
//
#include <hip/hip_runtime.h>
#include <math.h>

#define N_NODES 100000
#define N_EDGES 1600000
#define N_GRAPHS 128
#define IN_DIM 329
#define NH 4
#define CC 64
#define HC 256
#define NEG_SLOPE 0.2f
#define LOG2E 1.44269504f

#define K_PAD 384            // 6 * 64
#define M_PAD 100096         // 782 * 128
#define XBYTES (N_NODES * IN_DIM * 4)   // 131,600,000
#define NBUCK 196            // buckets of 512 nodes
#define BCAP 10240           // bucket capacity (expected 8673, +16 sigma)
#define EPB 8192             // edges per bin2 block

typedef unsigned short u16;
typedef unsigned char u8;
typedef unsigned int u32;
typedef __attribute__((ext_vector_type(8))) short short8;   // 8 bf16 (4 VGPRs)
typedef __attribute__((ext_vector_type(4))) float floatx4;
typedef __attribute__((ext_vector_type(2))) float floatx2;

__device__ __forceinline__ u16 f2bf(float f) {
    u32 u = __float_as_uint(f);
    u32 r = (u + 0x7FFFu + ((u >> 16) & 1u)) >> 16;   // RNE
    return (u16)r;
}

// pack two f32 -> two bf16 (truncation) in one v_perm_b32
__device__ __forceinline__ u32 pkbf(float a, float b) {
    return __builtin_amdgcn_perm(__float_as_uint(b), __float_as_uint(a), 0x07060302u);
}

// ---- fp8 e4m3 (OCP) helpers: HW path via cvt builtins, SW fallback --------
__device__ __forceinline__ u8 f2fp8(float f) {
#if __has_builtin(__builtin_amdgcn_cvt_pk_fp8_f32)
    int pk = __builtin_amdgcn_cvt_pk_fp8_f32(f, f, 0, false);
    return (u8)(pk & 0xFF);
#else
    u32 u = __float_as_uint(f);
    u32 sgn = (u >> 24) & 0x80;
    float af = fabsf(f);
    if (af >= 448.f) return (u8)(sgn | 0x7E);
    if (af < 0.015625f) {
        int m = (int)rintf(af * 512.f);
        if (m >= 8) return (u8)(sgn | 0x08);
        return (u8)(sgn | (u32)m);
    }
    u32 au = u & 0x7FFFFFFF;
    u32 r = au + 0x0007FFFFu + ((au >> 20) & 1u);
    u32 e = r >> 23;
    u32 m3 = (r >> 20) & 7;
    int fe = (int)e - 127 + 7;
    if (fe >= 16) return (u8)(sgn | 0x7E);
    return (u8)(sgn | ((u32)fe << 3) | m3);
#endif
}

__device__ __forceinline__ float fp82f_sw(u32 b) {
    u32 s = (b & 0x80u) << 24;
    u32 e = (b >> 3) & 0xF;
    u32 m = b & 7;
    if (e == 0) {
        float v = (float)m * 0.001953125f;
        return (b & 0x80) ? -v : v;
    }
    return __uint_as_float(s | ((e + 120) << 23) | (m << 20));
}

__device__ __forceinline__ floatx4 dec4(int p) {
#if __has_builtin(__builtin_amdgcn_cvt_pk_f32_fp8)
    floatx2 lo = __builtin_amdgcn_cvt_pk_f32_fp8(p, false);
    floatx2 hi = __builtin_amdgcn_cvt_pk_f32_fp8(p, true);
    floatx4 r; r.x = lo.x; r.y = lo.y; r.z = hi.x; r.w = hi.y;
    return r;
#else
    floatx4 r;
    r.x = fp82f_sw(p & 0xFF);  r.y = fp82f_sw((p >> 8) & 0xFF);
    r.z = fp82f_sw((p >> 16) & 0xFF); r.w = fp82f_sw((p >> 24) & 0xFF);
    return r;
#endif
}

__device__ __forceinline__ void async_copy16(const void* g, void* l) {
    __builtin_amdgcn_global_load_lds((const __attribute__((address_space(1))) void*)g,
                                     (__attribute__((address_space(3))) void*)l, 16, 0, 0);
}

__device__ __forceinline__ float sel4(float4 a, int h) {
    float lo = (h & 1) ? a.y : a.x;
    float hi = (h & 1) ? a.w : a.z;
    return (h & 2) ? hi : lo;
}

// ---------------------------------------------------------------------------
// Tiny convert: W (fp32 [329][256]) -> WbT (bf16 [256][K_PAD], transposed)
// ---------------------------------------------------------------------------
__global__ __launch_bounds__(256) void convw_kernel(const float* __restrict__ W, u16* __restrict__ WbT)
{
    int i = blockIdx.x * 256 + threadIdx.x;
    if (i >= HC * 96) return;
    int c = i / 96;
    int k0 = (i - c * 96) * 4;
    ushort4 o = {0, 0, 0, 0};
    const float* wp = W + c;
    if (k0 < IN_DIM)     o.x = f2bf(wp[(size_t)k0 * HC]);
    if (k0 + 1 < IN_DIM) o.y = f2bf(wp[(size_t)(k0 + 1) * HC]);
    if (k0 + 2 < IN_DIM) o.z = f2bf(wp[(size_t)(k0 + 2) * HC]);
    if (k0 + 3 < IN_DIM) o.w = f2bf(wp[(size_t)(k0 + 3) * HC]);
    *(ushort4*)(WbT + (size_t)c * K_PAD + k0) = o;
}

// ---------------------------------------------------------------------------
// MFMA GEMM with fused x conversion: stage x fp32 -> LDS (async, source-side
// XOR swizzle), pack to bf16 via v_perm at fragment read. Epilogue: fp8 store
// only. grid (782, 2), 256 threads.
// ---------------------------------------------------------------------------
__global__ __launch_bounds__(256) void gemm_mfma_kernel(
    const float* __restrict__ x, const u16* __restrict__ WbT, u8* __restrict__ xp8)
{
    __shared__ float Asf[128 * 64];   // 32 KB fp32, row = 16 chunks of 16B, chunk-XOR swizzled
    __shared__ u16 Bs[128 * 64];      // 16 KB bf16

    const int tid = threadIdx.x;
    const int lane = tid & 63;
    const int wave = tid >> 6;
    const int lr = lane & 15;
    const int q = lane >> 4;
    const int row0 = blockIdx.x * 128;
    const int col0 = blockIdx.y * 128;
    const int rm0 = (wave & 1) * 64;
    const int cn0 = (wave >> 1) * 64;

    floatx4 acc[4][4];
#pragma unroll
    for (int i = 0; i < 4; i++)
#pragma unroll
        for (int j = 0; j < 4; j++) {
            acc[i][j].x = 0.f; acc[i][j].y = 0.f; acc[i][j].z = 0.f; acc[i][j].w = 0.f;
        }

    for (int k0 = 0; k0 < K_PAD; k0 += 64) {
        // stage A: 128 rows x 64 fp32 = 32 KB, 8 chunks of 16B per thread.
        // physical chunk p at row r holds logical chunk (p ^ (r&15)).
#pragma unroll
        for (int t = 0; t < 8; t++) {
            int chunk = tid + t * 256;
            int row = chunk >> 4, ch = chunk & 15;
            int chl = ch ^ (row & 15);
            long gb = (long)(row0 + row) * (IN_DIM * 4) + (long)k0 * 4 + chl * 16;
            if (gb > (long)XBYTES - 16) gb = (long)XBYTES - 16;   // OOB-safe: garbage * B_zero = 0
            async_copy16((const char*)x + gb, (char*)Asf + (size_t)chunk * 16);
        }
        // stage B: 128 cols x 64 bf16 = 16 KB
#pragma unroll
        for (int t = 0; t < 4; t++) {
            int off = (tid + t * 256) * 16;
            int row = off >> 7;
            int col = off & 127;
            int gcol = col ^ ((row & 7) * 16);
            const char* gb = (const char*)WbT + (size_t)(col0 + row) * (K_PAD * 2) + k0 * 2 + gcol;
            async_copy16(gb, (char*)Bs + off);
        }
        __syncthreads();

        short8 af[2][4], bf[2][4];
#pragma unroll
        for (int ks = 0; ks < 2; ks++) {
#pragma unroll
            for (int i = 0; i < 4; i++) {
                int ra = rm0 + i * 16 + lr;
                int c0 = ks * 8 + q * 2;
                int sw = ra & 15;
                const float4* base = (const float4*)(Asf + ra * 64);
                float4 lo = base[c0 ^ sw];
                float4 hi = base[(c0 ^ sw) ^ 1];          // (c0+1)^sw == (c0^sw)^1 (c0 even)
                union { short8 v; u32 w[4]; } fr;
                fr.w[0] = pkbf(lo.x, lo.y);
                fr.w[1] = pkbf(lo.z, lo.w);
                fr.w[2] = pkbf(hi.x, hi.y);
                fr.w[3] = pkbf(hi.z, hi.w);
                af[ks][i] = fr.v;

                int rb = cn0 + i * 16 + lr;
                int cb = (ks * 64 + q * 16) ^ ((rb & 7) * 16);
                bf[ks][i] = *(const short8*)((const char*)Bs + rb * 128 + cb);
            }
        }
#pragma unroll
        for (int ks = 0; ks < 2; ks++)
#pragma unroll
            for (int i = 0; i < 4; i++)
#pragma unroll
                for (int j = 0; j < 4; j++)
                    acc[i][j] = __builtin_amdgcn_mfma_f32_16x16x32_bf16(af[ks][i], bf[ks][j], acc[i][j], 0, 0, 0);
        __syncthreads();
    }

    // epilogue: fp8 store (C/D layout: col=lane&15 block, row=q*4+reg)
#pragma unroll
    for (int i = 0; i < 4; i++) {
#pragma unroll
        for (int j = 0; j < 4; j++) {
            int col = col0 + cn0 + j * 16 + lr;
            float v[4] = {acc[i][j].x, acc[i][j].y, acc[i][j].z, acc[i][j].w};
#pragma unroll
            for (int r = 0; r < 4; r++) {
                int row = row0 + rm0 + i * 16 + q * 4 + r;
                if (row < N_NODES) xp8[(size_t)row * HC + col] = f2fp8(v[r]);
            }
        }
    }
}

// ---------------------------------------------------------------------------
// a_src/a_dst from fp8 xp, pre-scaled by log2(e) so aggregate can use exp2.
// ---------------------------------------------------------------------------
__global__ __launch_bounds__(256) void a8_kernel(
    const u8* __restrict__ xp8, const float* __restrict__ att_src, const float* __restrict__ att_dst,
    float* __restrict__ a_src, float* __restrict__ a_dst)
{
    int n = blockIdx.x * 4 + (threadIdx.x >> 6);
    int lane = threadIdx.x & 63;
    if (n >= N_NODES) return;
    int h = lane >> 4;
    int c0 = (lane & 15) * 4;
    int p = *(const int*)(xp8 + (size_t)n * HC + h * CC + c0);
    floatx4 v = dec4(p);
    const float* as = att_src + h * CC + c0;
    const float* ad = att_dst + h * CC + c0;
    float ps = v.x * as[0] + v.y * as[1] + v.z * as[2] + v.w * as[3];
    float pd = v.x * ad[0] + v.y * ad[1] + v.z * ad[2] + v.w * ad[3];
#pragma unroll
    for (int m = 1; m < 16; m <<= 1) {
        ps += __shfl_xor(ps, m, 64);
        pd += __shfl_xor(pd, m, 64);
    }
    if ((lane & 15) == 0) {
        a_src[n * 4 + h] = ps * LOG2E;
        a_dst[n * 4 + h] = pd * LOG2E;
    }
}

// ---------------------------------------------------------------------------
// Pass 1: bucket-bin edges. Block-local reservation (gpos) keeps each run's
// lines written by one block/XCD -> L2 write-combining works (R5/R6 lesson).
// ---------------------------------------------------------------------------
__global__ __launch_bounds__(256) void bin2_kernel(
    const int* __restrict__ ei, int* __restrict__ bcur, int2* __restrict__ bins)
{
    __shared__ int hist[NBUCK];
    __shared__ int gpos[NBUCK];
    __shared__ int lcur[NBUCK];
    __shared__ int sc[256];

    const int t = threadIdx.x;
    const int lo = blockIdx.x * EPB;
    const int hi = min(lo + EPB, N_EDGES + N_NODES);

    for (int b = t; b < NBUCK; b += 256) hist[b] = 0;
    __syncthreads();

    for (int i = lo + t; i < hi; i += 256) {
        int d = (i < N_EDGES) ? ei[N_EDGES + i] : (i - N_EDGES);
        atomicAdd(&hist[d >> 9], 1);
    }
    __syncthreads();

    int v = (t < NBUCK) ? hist[t] : 0;
    if (t < NBUCK) { gpos[t] = atomicAdd(&bcur[t], v); lcur[t] = 0; }
    (void)sc;
    __syncthreads();

    for (int i = lo + t; i < hi; i += 256) {
        int s, d;
        if (i < N_EDGES) { s = ei[i]; d = ei[N_EDGES + i]; }
        else             { s = i - N_EDGES; d = s; }
        int b = d >> 9;
        int pos = gpos[b] + atomicAdd(&lcur[b], 1);
        if (pos < BCAP) {
            int2 r; r.x = s; r.y = d;
            bins[(size_t)b * BCAP + pos] = r;
        }
    }
}

// ---------------------------------------------------------------------------
// Pass 2: one 512-thread block per bucket. LDS counting sort -> compact CSR.
// ---------------------------------------------------------------------------
__global__ __launch_bounds__(512) void fill3_kernel(
    const int* __restrict__ bcur, const int2* __restrict__ bins,
    int2* __restrict__ rs_deg, int* __restrict__ csr)
{
    __shared__ int deg[512];
    __shared__ int cur[512];
    __shared__ int sc[256];
    __shared__ int order[BCAP];

    const int t = threadIdx.x;
    const int b = blockIdx.x;
    const int cnt = min(bcur[b], BCAP);
    const int2* bp = bins + (size_t)b * BCAP;
    const int gbase = b * BCAP;

    deg[t] = 0;
    __syncthreads();
    for (int i = t; i < cnt; i += 512) atomicAdd(&deg[bp[i].y & 511], 1);
    __syncthreads();

    int d0 = 0, d1 = 0;
    if (t < 256) {
        d0 = deg[2 * t]; d1 = deg[2 * t + 1];
        sc[t] = d0 + d1;
    }
    __syncthreads();
    for (int off = 1; off < 256; off <<= 1) {
        int u = (t < 256 && t >= off) ? sc[t - off] : 0;
        __syncthreads();
        if (t < 256) sc[t] += u;
        __syncthreads();
    }
    if (t < 256) {
        int excl = sc[t] - (d0 + d1);
        cur[2 * t] = excl;
        cur[2 * t + 1] = excl + d0;
        int n0 = b * 512 + 2 * t;
        if (n0 < N_NODES)     { int2 rd; rd.x = gbase + excl;      rd.y = d0; rs_deg[n0] = rd; }
        if (n0 + 1 < N_NODES) { int2 rd; rd.x = gbase + excl + d0; rd.y = d1; rs_deg[n0 + 1] = rd; }
    }
    __syncthreads();

    for (int i = t; i < cnt; i += 512) {
        int2 r = bp[i];
        int pos = atomicAdd(&cur[r.y & 511], 1);
        order[pos] = r.x;
    }
    __syncthreads();

    for (int i = t; i < cnt; i += 512) csr[gbase + i] = order[i];
}

// ---------------------------------------------------------------------------
// Fused single-pass segment softmax + fp8 aggregation + head-mean + bias/relu.
// a_src/a_dst pre-scaled by log2(e) -> exp2f. 32-bit gather offsets.
// ---------------------------------------------------------------------------
__global__ __launch_bounds__(256) void aggregate_kernel(
    const u8* __restrict__ xp8, const float* __restrict__ a_src, const float* __restrict__ a_dst,
    const int2* __restrict__ rs_deg, const int* __restrict__ csr,
    const float* __restrict__ bias, float* __restrict__ hbuf)
{
    int n = blockIdx.x * 4 + (threadIdx.x >> 6);
    int lane = threadIdx.x & 63;
    if (n >= N_NODES) return;
    int2 rd = rs_deg[n];
    int rstart = __builtin_amdgcn_readfirstlane(rd.x);
    int deg    = __builtin_amdgcn_readfirstlane(rd.y);
    const int* ep = csr + rstart;
    int h = lane >> 4;
    int xoff = lane * 4;

    float ad = a_dst[n * 4 + h];

    float acc0 = 0.f, acc1 = 0.f, acc2 = 0.f, acc3 = 0.f, den = 0.f;
    int e = 0;
    for (; e + 4 <= deg; e += 4) {
        int s0 = ep[e], s1 = ep[e + 1], s2 = ep[e + 2], s3 = ep[e + 3];
        float4 A0 = *(const float4*)(a_src + s0 * 4);
        float4 A1 = *(const float4*)(a_src + s1 * 4);
        float4 A2 = *(const float4*)(a_src + s2 * 4);
        float4 A3 = *(const float4*)(a_src + s3 * 4);
        int p0 = *(const int*)(xp8 + s0 * HC + xoff);
        int p1 = *(const int*)(xp8 + s1 * HC + xoff);
        int p2 = *(const int*)(xp8 + s2 * HC + xoff);
        int p3 = *(const int*)(xp8 + s3 * HC + xoff);
        float z0 = sel4(A0, h) + ad, z1 = sel4(A1, h) + ad;
        float z2 = sel4(A2, h) + ad, z3 = sel4(A3, h) + ad;
        float w0 = exp2f(fmaxf(z0, NEG_SLOPE * z0));
        float w1 = exp2f(fmaxf(z1, NEG_SLOPE * z1));
        float w2 = exp2f(fmaxf(z2, NEG_SLOPE * z2));
        float w3 = exp2f(fmaxf(z3, NEG_SLOPE * z3));
        den += (w0 + w1) + (w2 + w3);
        floatx4 v0 = dec4(p0), v1 = dec4(p1), v2 = dec4(p2), v3 = dec4(p3);
        acc0 = fmaf(w0, v0.x, acc0); acc1 = fmaf(w0, v0.y, acc1);
        acc2 = fmaf(w0, v0.z, acc2); acc3 = fmaf(w0, v0.w, acc3);
        acc0 = fmaf(w1, v1.x, acc0); acc1 = fmaf(w1, v1.y, acc1);
        acc2 = fmaf(w1, v1.z, acc2); acc3 = fmaf(w1, v1.w, acc3);
        acc0 = fmaf(w2, v2.x, acc0); acc1 = fmaf(w2, v2.y, acc1);
        acc2 = fmaf(w2, v2.z, acc2); acc3 = fmaf(w2, v2.w, acc3);
        acc0 = fmaf(w3, v3.x, acc0); acc1 = fmaf(w3, v3.y, acc1);
        acc2 = fmaf(w3, v3.z, acc2); acc3 = fmaf(w3, v3.w, acc3);
    }
    for (; e < deg; e++) {
        int s0 = ep[e];
        float4 A0 = *(const float4*)(a_src + s0 * 4);
        int p0 = *(const int*)(xp8 + s0 * HC + xoff);
        float z0 = sel4(A0, h) + ad;
        float w0 = exp2f(fmaxf(z0, NEG_SLOPE * z0));
        den += w0;
        floatx4 v0 = dec4(p0);
        acc0 = fmaf(w0, v0.x, acc0); acc1 = fmaf(w0, v0.y, acc1);
        acc2 = fmaf(w0, v0.z, acc2); acc3 = fmaf(w0, v0.w, acc3);
    }

    float r = 1.f / den;
    acc0 *= r; acc1 *= r; acc2 *= r; acc3 *= r;
#pragma unroll
    for (int m = 16; m <= 32; m <<= 1) {
        acc0 += __shfl_xor(acc0, m, 64);
        acc1 += __shfl_xor(acc1, m, 64);
        acc2 += __shfl_xor(acc2, m, 64);
        acc3 += __shfl_xor(acc3, m, 64);
    }
    if (lane < 16) {
        const float* bp = bias + lane * 4;
        float4 o;
        o.x = fmaxf(0.25f * acc0 + bp[0], 0.f);
        o.y = fmaxf(0.25f * acc1 + bp[1], 0.f);
        o.z = fmaxf(0.25f * acc2 + bp[2], 0.f);
        o.w = fmaxf(0.25f * acc3 + bp[3], 0.f);
        *(float4*)&hbuf[(size_t)n * CC + lane * 4] = o;
    }
}

// ---------------------------------------------------------------------------
// Pool pass 1: per-wave running sums over sorted batch, flush on boundary.
// ---------------------------------------------------------------------------
__global__ __launch_bounds__(256) void pool1_kernel(
    const float* __restrict__ hbuf, const int* __restrict__ batch,
    float* __restrict__ gsum, int* __restrict__ gcnt)
{
    int w = threadIdx.x >> 6, lane = threadIdx.x & 63;
    int r0 = blockIdx.x * 128 + w * 32;
    if (r0 >= N_NODES) return;
    int r1 = min(r0 + 32, N_NODES);
    int cur = batch[r0];
    float s = 0.f;
    int c = 0;
    for (int r = r0; r < r1; r++) {
        int bb = batch[r];
        if (bb != cur) {
            atomicAdd(&gsum[cur * 64 + lane], s);
            if (lane == 0) atomicAdd(&gcnt[cur], c);
            s = 0.f; c = 0; cur = bb;
        }
        s += hbuf[(size_t)r * CC + lane];
        c++;
    }
    atomicAdd(&gsum[cur * 64 + lane], s);
    if (lane == 0) atomicAdd(&gcnt[cur], c);
}

// Pool pass 2: per-graph MLP head.
__global__ __launch_bounds__(64) void pool2_kernel(
    const float* __restrict__ gsum, const int* __restrict__ gcnt,
    const float* __restrict__ w1, const float* __restrict__ b1,
    const float* __restrict__ w2, const float* __restrict__ b2,
    float* __restrict__ out)
{
    int g = blockIdx.x;
    int lane = threadIdx.x;
    __shared__ float gv[64];
    gv[lane] = gsum[g * 64 + lane] / (float)max(gcnt[g], 1);
    __syncthreads();
    float hid = b1[lane];
    for (int c = 0; c < 64; c++) hid = fmaf(gv[c], w1[c * 64 + lane], hid);
    hid = fmaxf(hid, 0.f);
    float part = hid * w2[lane];
#pragma unroll
    for (int off = 32; off > 0; off >>= 1) part += __shfl_xor(part, off, 64);
    if (lane == 0) out[g] = 1.f / (1.f + __expf(-(part + b2[0])));
}

// ---------------------------------------------------------------------------
extern "C" void kernel_launch(void* const* d_in, const int* in_sizes, int n_in,
                              void* d_out, int out_size, void* d_ws, size_t ws_size,
                              hipStream_t stream)
{
    const float* x       = (const float*)d_in[0];
    const float* W       = (const float*)d_in[1];
    const float* att_src = (const float*)d_in[2];
    const float* att_dst = (const float*)d_in[3];
    const float* bias    = (const float*)d_in[4];
    const float* w1      = (const float*)d_in[5];
    const float* b1      = (const float*)d_in[6];
    const float* w2      = (const float*)d_in[7];
    const float* b2      = (const float*)d_in[8];
    const int*   ei      = (const int*)d_in[9];
    const int*   batch   = (const int*)d_in[10];
    float* out = (float*)d_out;

    char* ws = (char*)d_ws;
    size_t off = 0;
    auto alloc = [&](size_t bytes) -> void* {
        void* p = ws + off;
        off += (bytes + 255) & ~(size_t)255;
        return p;
    };
    u16*   WbT       = (u16*)alloc((size_t)HC * K_PAD * 2);             // 196 KB
    u8*    xp8       = (u8*)alloc((size_t)N_NODES * HC);                // 25.6 MB
    float* a_src_b   = (float*)alloc((size_t)N_NODES * NH * 4);
    float* a_dst_b   = (float*)alloc((size_t)N_NODES * NH * 4);
    size_t zoff0 = off;
    int*   bcur      = (int*)alloc((size_t)NBUCK * 4);                  // zeroed
    float* gsum      = (float*)alloc((size_t)N_GRAPHS * 64 * 4);        // zeroed
    int*   gcnt      = (int*)alloc((size_t)N_GRAPHS * 4);               // zeroed
    size_t zbytes = off - zoff0;
    int2*  bins      = (int2*)alloc((size_t)NBUCK * BCAP * 8);          // 16.1 MB
    int2*  rs_deg    = (int2*)alloc((size_t)N_NODES * 8);               // 800 KB
    int*   csr       = (int*)alloc((size_t)NBUCK * BCAP * 4);           // 8 MB
    float* hbuf      = (float*)alloc((size_t)N_NODES * CC * 4);         // 25.6 MB

    hipMemsetAsync(bcur, 0, zbytes, stream);

    convw_kernel<<<(HC * 96 + 255) / 256, 256, 0, stream>>>(W, WbT);

    dim3 ggrid(M_PAD / 128, 2);
    gemm_mfma_kernel<<<ggrid, 256, 0, stream>>>(x, WbT, xp8);

    a8_kernel<<<(N_NODES + 3) / 4, 256, 0, stream>>>(xp8, att_src, att_dst, a_src_b, a_dst_b);

    int tot = N_EDGES + N_NODES;
    bin2_kernel<<<(tot + EPB - 1) / EPB, 256, 0, stream>>>(ei, bcur, bins);
    fill3_kernel<<<NBUCK, 512, 0, stream>>>(bcur, bins, rs_deg, csr);

    aggregate_kernel<<<(N_NODES + 3) / 4, 256, 0, stream>>>(xp8, a_src_b, a_dst_b,
                                                            rs_deg, csr, bias, hbuf);

    pool1_kernel<<<(N_NODES + 127) / 128, 256, 0, stream>>>(hbuf, batch, gsum, gcnt);
    pool2_kernel<<<N_GRAPHS, 64, 0, stream>>>(gsum, gcnt, w1, b1, w2, b2, out);
}